// Round 11
// baseline (562.218 us; speedup 1.0000x reference)
//
#include <hip/hip_runtime.h>
#include <hip/hip_bf16.h>
#include <hip/hip_fp16.h>
#include <math.h>

#define NN   100000   // nodes
#define NNP  100096   // nodes padded to mult of 128 (GEMM staging reads, zero-filled)
#define DD   202      // feature dim
#define ET   6        // edge types
#define MM   200000   // edges per type
#define NE   (ET*MM)  // 1.2M edges
#define NPOS 512
#define GDP  204      // gating row stride (fp16 elements; 408-B rows, zeros at 202..203)
#define DE   1212     // DD*ET
#define PDE  1216     // prop row stride (padded; 2432 B rows -> 16B-aligned, 64B-aligned)
#define KK   202      // GEMM K
#define KP   224      // K padded to 7*32
#define NP   1280     // N padded to 10*128

// fused_prep geometry: [0,512)=gating | [512,1632)=convB | then 1564 groups of
// (7 convA + 3 count).
#define NB_CONVB 1120
#define NB_CA    10948     // NNP*28/256 exact
#define PREPG    1564      // 1564*7 = 10948 convA (exact); 1564*3 = 4692 >= 4688 count
#define GEMM_WGS 7820      // (NP/128)*(NNP/128) = 10*782
#define NB_SCAT  4688      // ceil(NE/256)

typedef __attribute__((ext_vector_type(8))) short bf16x8;
typedef __attribute__((ext_vector_type(4))) float f32x4;

static __device__ inline unsigned short f2b(float f) {
    union { __hip_bfloat16 h; unsigned short s; } u;
    u.h = __float2bfloat16(f);
    return u.s;
}

static __device__ inline void glds16(const unsigned short* g, unsigned short* l) {
    __builtin_amdgcn_global_load_lds(
        (const __attribute__((address_space(1))) unsigned int*)g,
        (__attribute__((address_space(3))) unsigned int*)l, 16, 0, 0);
}

// ---------------- fused prep: gating | convB | convA (vectorized) | count
// (byte-exact round-8 code path; count hides under convA's BW work)
__global__ __launch_bounds__(256) void fused_prep(const float* __restrict__ W_pos,
                                                  const float* __restrict__ b_pos,
                                                  unsigned short* __restrict__ gat,
                                                  const float* __restrict__ W,
                                                  unsigned short* __restrict__ Bt,
                                                  const float* __restrict__ A,
                                                  unsigned short* __restrict__ Abf,
                                                  const int* __restrict__ edges,
                                                  int* __restrict__ count) {
    __shared__ float emb[DD];
    int bid = blockIdx.x;
    int t = threadIdx.x;

    if (bid < NPOS) {
        // ---- pos_gating: (512 x GDP) fp16 = 2*sigmoid(pos_embs @ W_pos + b_pos)
        int p = bid;
        if (t < 100) {
            float invf = expf(-((float)t / 100.0f) * 9.210340371976184f); // ln(10000)
            float si = (float)p * invf;
            emb[t]       = sinf(si);
            emb[100 + t] = cosf(si);
        } else if (t < 102) {
            emb[100 + t] = 0.0f;
        }
        __syncthreads();
        if (t < GDP) {
            float g = 0.0f;
            if (t < DD) {
                float acc = b_pos[t];
                for (int k = 0; k < DD; ++k) acc += emb[k] * W_pos[k * DD + t];
                g = 2.0f / (1.0f + expf(-acc));
            }
            union { __half h; unsigned short s; } u;
            u.h = __float2half_rn(g);
            gat[p * GDP + t] = u.s;   // fp16; zeros at 202,203
        }
        return;
    }
    bid -= NPOS;

    if (bid < NB_CONVB) {
        // ---- W_transform (202x1212 fp32) -> Bt (1280x224 bf16, transposed, padded)
        int id = bid * 256 + t;            // < NP*KP exactly
        int n = id / KP, k = id % KP;
        float v = (k < KK && n < DE) ? W[(size_t)k * DE + n] : 0.0f;
        Bt[id] = f2b(v);
        return;
    }
    bid -= NB_CONVB;

    int g = bid / 10, s = bid % 10;
    if (s < 7) {
        // ---- convA: node_states (100000x202 fp32) -> Abf (100096x224 bf16)
        int ca = g * 7 + s;                // < NB_CA exactly
        int id = ca * 256 + t;             // < NNP*28
        int row = id / 28;
        int kp  = (id % 28) * 8;
        bf16x8 o;
        #pragma unroll
        for (int j = 0; j < 8; ++j) o[j] = 0;
        if (row < NN) {
            const float* ar = A + (size_t)row * KK;
            #pragma unroll
            for (int j = 0; j < 4; ++j) {
                if (kp + 2 * j + 1 < KK) {           // KK even: pairs never straddle
                    float2 v = *(const float2*)&ar[kp + 2 * j];
                    o[2 * j]     = (short)f2b(v.x);
                    o[2 * j + 1] = (short)f2b(v.y);
                }
            }
        }
        *(bf16x8*)&Abf[(size_t)row * KP + kp] = o;   // 16B-aligned
    } else {
        // ---- count: histogram of targets
        int cid = g * 3 + (s - 7);
        int i = cid * 256 + t;
        if (i < NE) atomicAdd(&count[edges[2 * i + 1]], 1);
    }
}

// ---------------- pass 2: segment allocation (block scan + 1 atomic/block)
__global__ __launch_bounds__(256) void alloc_kernel(const int* __restrict__ count,
                                                    int* __restrict__ start,
                                                    int* __restrict__ cursor) {
    int t = blockIdx.x * 256 + threadIdx.x;
    int c = (t < NN) ? count[t] : 0;
    __shared__ int s[256];
    __shared__ int base;
    s[threadIdx.x] = c;
    __syncthreads();
    int v = c;
    for (int off = 1; off < 256; off <<= 1) {
        int u = (threadIdx.x >= off) ? s[threadIdx.x - off] : 0;
        __syncthreads();
        v += u;
        s[threadIdx.x] = v;
        __syncthreads();
    }
    if (threadIdx.x == 255) base = atomicAdd(cursor, v);
    __syncthreads();
    if (t < NN) start[t] = base + v - c;
}

// ---------------- pass 3: scatter PACKED edge records (start becomes segment END)
// record: src (17b) | e (3b) | pos (9b)   (byte-exact round-8 code path)
__global__ __launch_bounds__(256) void scatter_kernel(const int* __restrict__ edges,
                                                      const int* __restrict__ pos_lists,
                                                      int* __restrict__ start,
                                                      unsigned* __restrict__ recs) {
    int i = blockIdx.x * 256 + threadIdx.x;
    if (i >= NE) return;
    int2 st = *(const int2*)&edges[2 * i];              // (src, tgt), 8B aligned
    int e = (int)((unsigned)i / MM);                    // edge type
    unsigned rec = (unsigned)st.x | ((unsigned)e << 17) | ((unsigned)pos_lists[i] << 20);
    int p = atomicAdd(&start[st.y], 1);
    recs[p] = rec;
}

// ---------------- PURE GEMM: prop = Abf @ Bt^T + b -> bf16[NN][PDE]
// MFMA 128x128 tile, 2-phase counted-vmcnt double-buffer, bijective XCD-chunk
// swizzle (proven: FETCH 122->32 MB).  Byte-exact round-8 GEMM branch.
__global__ __launch_bounds__(256) void gemm_kernel(const unsigned short* __restrict__ Abf,
                                                   const unsigned short* __restrict__ Bt,
                                                   const float* __restrict__ bias,
                                                   unsigned short* __restrict__ C) {
    __shared__ unsigned short lds[16384];    // 32 KB
    int b = blockIdx.x;

    // bijective XCD-chunk map: XCD x (= b%8) owns a contiguous lin-range.
    int x = b & 7, i0 = b >> 3;
    int lin = (x < 4) ? x * 978 + i0 : 3912 + (x - 4) * 977 + i0;
    int row0 = (lin / 10) * 128;
    int col0 = (lin % 10) * 128;

    unsigned short* sA = lds;               // [2][4096] (128 rows x 32 k per buf)
    unsigned short* sB = lds + 8192;        // [2][4096]
    unsigned short* sE = lds;               // epilogue alias (safe after final barrier)

    int t    = threadIdx.x;
    int lane = t & 63;
    int wave = t >> 6;
    int q    = lane >> 4;
    int r16  = lane & 15;
    int wm   = (wave >> 1) * 64;
    int wn   = (wave & 1) * 64;

    // staging geometry: lane covers 16B; rows wave*32+i*16+lrow; chunk XOR-swizzled
    int lrow = lane >> 2;
    int gch  = (lane & 3) ^ ((lrow >> 1) & 3);
    const unsigned short* aS0 = Abf + (size_t)(row0 + wave * 32 + lrow) * KP + gch * 8;
    const unsigned short* aS1 = aS0 + 16 * KP;
    const unsigned short* bS0 = Bt  + (size_t)(col0 + wave * 32 + lrow) * KP + gch * 8;
    const unsigned short* bS1 = bS0 + 16 * KP;

#define STAGE(bf, kc) do {                                   \
        glds16(aS0 + (kc), &sA[(bf)*4096 + wave*1024]);      \
        glds16(aS1 + (kc), &sA[(bf)*4096 + wave*1024+512]);  \
        glds16(bS0 + (kc), &sB[(bf)*4096 + wave*1024]);      \
        glds16(bS1 + (kc), &sB[(bf)*4096 + wave*1024+512]);  \
    } while (0)

    f32x4 acc[4][4] = {};
    int swzr = (r16 >> 1) & 3;

    STAGE(0, 0);
    for (int k = 0; k < 7; ++k) {
        int cur = k & 1;
        if (k < 6) {
            STAGE(cur ^ 1, (k + 1) * 32);                       // 4 more in flight
            asm volatile("s_waitcnt vmcnt(4)" ::: "memory");    // stage k landed
        } else {
            asm volatile("s_waitcnt vmcnt(0)" ::: "memory");
        }
        __builtin_amdgcn_s_barrier();      // all waves' stage-k visible

        bf16x8 a[4], bb2[4];
        int sbase = cur * 4096;
        #pragma unroll
        for (int mi = 0; mi < 4; ++mi)
            a[mi] = *(const bf16x8*)&sA[sbase + (wm + mi * 16 + r16) * 32 + (q ^ swzr) * 8];
        #pragma unroll
        for (int ni = 0; ni < 4; ++ni)
            bb2[ni] = *(const bf16x8*)&sB[sbase + (wn + ni * 16 + r16) * 32 + (q ^ swzr) * 8];
        #pragma unroll
        for (int mi = 0; mi < 4; ++mi)
            #pragma unroll
            for (int ni = 0; ni < 4; ++ni)
                acc[mi][ni] = __builtin_amdgcn_mfma_f32_16x16x32_bf16(a[mi], bb2[ni], acc[mi][ni], 0, 0, 0);

        __builtin_amdgcn_s_barrier();      // buf 'cur' reads retired before overwrite
    }
#undef STAGE

    // epilogue: per-wave-private LDS staging -> 16B/lane aligned stores
    float bb[4];
    #pragma unroll
    for (int ni = 0; ni < 4; ++ni) {
        int col = col0 + wn + ni * 16 + r16;
        bb[ni] = (col < DE) ? bias[col] : 0.0f;
    }
    int epi = wave * 1152;            // 16 rows * 72
    int rl = lane >> 3, ck = lane & 7;
    #pragma unroll
    for (int mi = 0; mi < 4; ++mi) {
        #pragma unroll
        for (int ni = 0; ni < 4; ++ni)
            #pragma unroll
            for (int ri = 0; ri < 4; ++ri)
                sE[epi + (q * 4 + ri) * 72 + ni * 16 + r16] = f2b(acc[mi][ni][ri] + bb[ni]);
        #pragma unroll
        for (int ii = 0; ii < 2; ++ii) {
            int rr = ii * 8 + rl;
            bf16x8 v = *(const bf16x8*)&sE[epi + rr * 72 + ck * 8];
            int grow = row0 + wm + mi * 16 + rr;
            int gcol = col0 + wn + ck * 8;
            if (grow < NN && gcol < PDE)
                *(bf16x8*)&C[(size_t)grow * PDE + gcol] = v;
        }
    }
}

// ---------------- gather: one wave per target (byte-exact round-8 code path)
__global__ __launch_bounds__(256) void gather_kernel(const unsigned short* __restrict__ prop,
                                                     const unsigned short* __restrict__ gat,
                                                     const int* __restrict__ count,
                                                     const int* __restrict__ seg_end,
                                                     const unsigned* __restrict__ recs,
                                                     float* __restrict__ out) {
    int wid = blockIdx.x * 4 + (threadIdx.x >> 6);
    if (wid >= NN) return;
    int lane = threadIdx.x & 63;
    int c = count[wid];
    int end = seg_end[wid];
    int begin = end - c;
    int d = lane * 4;
    bool act = d < DD;                    // lanes 0..50
    float a0 = 0.f, a1 = 0.f, a2 = 0.f, a3 = 0.f;

    for (int base = begin; base < end; base += 64) {
        int n = end - base; if (n > 64) n = 64;
        unsigned rec = 0u;
        if (lane < n) rec = recs[base + lane];
        int poff = (int)(rec & 0x1FFFFu) * PDE + (int)((rec >> 17) & 7u) * DD;  // elems
        int goff = (int)(rec >> 20) * GDP;                                      // elems

        for (int jj = 0; jj < n; jj += 4) {
            int po[4], go[4];
            #pragma unroll
            for (int u = 0; u < 4; ++u) {
                int j = jj + u; if (j >= n) j = jj;     // clamped dups: L1-hit, unused
                po[u] = __shfl(poff, j);
                go[u] = __shfl(goff, j);
            }
            uint2 pv[4], gv[4];
            #pragma unroll
            for (int u = 0; u < 4; ++u) {
                pv[u] = make_uint2(0u, 0u);
                gv[u] = make_uint2(0u, 0u);
                if (act) {
                    pv[u] = *(const uint2*)&prop[po[u] + d];
                    gv[u] = *(const uint2*)&gat[go[u] + d];
                }
            }
            #pragma unroll
            for (int u = 0; u < 4; ++u) {
                if (jj + u < n || u == 0) {             // n wave-uniform: scalar branch
                    float2 g01 = __half22float2(*(const __half2*)&gv[u].x);
                    float2 g23 = __half22float2(*(const __half2*)&gv[u].y);
                    a0 += __uint_as_float(pv[u].x << 16)         * g01.x;
                    a1 += __uint_as_float(pv[u].x & 0xffff0000u) * g01.y;
                    a2 += __uint_as_float(pv[u].y << 16)         * g23.x;
                    a3 += __uint_as_float(pv[u].y & 0xffff0000u) * g23.y;
                }
            }
        }
    }

    float div = (c == 0 ? 1.0f : (float)c) + 1e-8f;
    float inv = 1.0f / div;
    if (act) {
        float* orow = out + (size_t)wid * DD;
        *(float2*)&orow[d] = make_float2(a0 * inv, a1 * inv);
        if (d + 2 < DD) *(float2*)&orow[d + 2] = make_float2(a2 * inv, a3 * inv);
    }
}

extern "C" void kernel_launch(void* const* d_in, const int* in_sizes, int n_in,
                              void* d_out, int out_size, void* d_ws, size_t ws_size,
                              hipStream_t stream) {
    const float* node_states = (const float*)d_in[0];
    const int*   edges       = (const int*)d_in[1];
    const int*   pos_lists   = (const int*)d_in[2];
    const float* W_transform = (const float*)d_in[3];
    const float* b_transform = (const float*)d_in[4];
    const float* W_pos       = (const float*)d_in[5];
    const float* b_pos       = (const float*)d_in[6];
    float* out = (float*)d_out;

    // workspace layout — byte-exact round-8 footprint (294,425,360 B, proven)
    char* ws = (char*)d_ws;
    unsigned short* gat = (unsigned short*)ws;  ws += (size_t)NPOS * GDP * 2;  // 208,896 B
    int* count  = (int*)ws;                     ws += (size_t)NN * 4;          // 400,000 B
    int* start  = (int*)ws;                     ws += (size_t)NN * 4;          // 400,000 B
    int* cursor = (int*)ws;                     ws += 16;
    unsigned short* Bt  = (unsigned short*)ws;  ws += (size_t)NP * KP * 2;     // 573,440 B
    unsigned short* Abf = (unsigned short*)ws;  ws += (size_t)NNP * KP * 2;    // 44,843,008 B
    unsigned* recs = (unsigned*)ws;             ws += (size_t)NE * 4;          // 4,800,000 B
    unsigned short* prop = (unsigned short*)ws;                                // 243,200,000 B

    hipMemsetAsync(count, 0, NN * sizeof(int), stream);
    hipMemsetAsync(cursor, 0, sizeof(int), stream);

    // 1. gating | convB | convA | count   (count hidden under convA)
    fused_prep<<<NPOS + NB_CONVB + PREPG * 10, 256, 0, stream>>>(
        W_pos, b_pos, gat, W_transform, Bt, node_states, Abf, edges, count);

    // 2. segment allocation (needs count)
    alloc_kernel<<<(NN + 255) / 256, 256, 0, stream>>>(count, start, cursor);

    // 3. scatter (standalone — exposes its true cost)
    scatter_kernel<<<NB_SCAT, 256, 0, stream>>>(edges, pos_lists, start, recs);

    // 4. pure GEMM (clean measurement)
    gemm_kernel<<<GEMM_WGS, 256, 0, stream>>>(Abf, Bt, b_transform, prop);

    // 5. gather
    gather_kernel<<<(NN + 3) / 4, 256, 0, stream>>>(prop, gat, count, start, recs, out);
}